// Round 4
// baseline (396.720 us; speedup 1.0000x reference)
//
#include <hip/hip_runtime.h>
#include <hip/hip_bf16.h>

#define VOCAB 256
#define EMB   32
#define HID   128
#define GATES 512
#define BATCH 512
#define SEQ   512

typedef __attribute__((ext_vector_type(8))) short bf16x8;
typedef __attribute__((ext_vector_type(4))) float f32x4;

static __device__ __forceinline__ unsigned short f2bf(float f) {
  unsigned int u = __float_as_uint(f);
  return (unsigned short)((u + 0x7fffu + ((u >> 16) & 1u)) >> 16);
}

// ws layout: P[VOCAB][GATES] f32 (512 KB) | Whh_bf16[GATES][HID] (128 KB)
__global__ __launch_bounds__(256) void prep_kernel(
    const float* __restrict__ emb, const float* __restrict__ W_ih,
    const float* __restrict__ W_hh, const float* __restrict__ b_ih,
    const float* __restrict__ b_hh, float* __restrict__ P,
    unsigned short* __restrict__ Whh_bf) {
  const int wg  = blockIdx.x;
  const int tid = threadIdx.x;
  if (wg < VOCAB) {
    __shared__ float e[EMB];
    if (tid < EMB) e[tid] = emb[wg * EMB + tid];
    __syncthreads();
    for (int g = tid; g < GATES; g += 256) {
      float acc = b_ih[g] + b_hh[g];
      const float* w = W_ih + g * EMB;
      #pragma unroll
      for (int k = 0; k < EMB; ++k) acc += e[k] * w[k];
      P[wg * GATES + g] = acc;
    }
  } else {
    const int base = (wg - VOCAB) * 1024 + tid * 4;
    const float4 v = *(const float4*)(W_hh + base);
    ushort4 o;
    o.x = f2bf(v.x); o.y = f2bf(v.y); o.z = f2bf(v.z); o.w = f2bf(v.w);
    *(ushort4*)(Whh_bf + base) = o;
  }
}

// 256 WGs x 512 threads (8 waves = 2/SIMD for latency hiding).
// WG owns batch rows {2wg, 2wg+1}. Wave w owns hidden columns
// j in [16w,16w+16) for ALL 4 gate types: n-tile u=gt, gate g = gt*128+16w+c16.
// A row m reads h[m&1] => D reg r holds batch row (r&1) for every lane.
// Lane (c16,kg) does gate math for (row=kg&1, j=16w+c16); kg>>1 duplicates
// are benign (same value, same address). One barrier per step.
__global__ __launch_bounds__(512, 2) void lstm_kernel(
    const int* __restrict__ inputs, const float* __restrict__ P,
    const unsigned short* __restrict__ Whh_bf,
    const float* __restrict__ W_cls, const float* __restrict__ b_cls,
    float* __restrict__ out) {
  const int wg   = blockIdx.x;
  const int tid  = threadIdx.x;
  const int wave = tid >> 6;          // 0..7
  const int lane = tid & 63;
  const int c16  = lane & 15;
  const int kg   = lane >> 4;
  const int b0   = wg * 2;

  const int row   = kg & 1;                    // this lane's batch row
  const int jfull = wave * 16 + c16;           // 0..127 hidden index

  __shared__ unsigned char  chars[2][SEQ];     // 1 KB
  __shared__ unsigned short hbuf[2][2][HID];   // [buf][row][k] bf16, 1 KB
  __shared__ float          h_last[2][HID];    // 1 KB

  for (int k = tid; k < 2 * SEQ; k += 512) {
    const int r = k >> 9, t = k & (SEQ - 1);
    chars[r][t] = (unsigned char)(inputs[(b0 + r) * SEQ + t] & 0xff);
  }
  if (tid < 512) ((unsigned short*)hbuf)[tid] = 0;   // zero both h buffers

  // B-frags resident: Bfrag[gt][ks] lane (c16,kg) = W_hh[gt*128+16w+c16][ks*32+kg*8..+7]
  bf16x8 Bfrag[4][4];
  #pragma unroll
  for (int gt = 0; gt < 4; ++gt) {
    const int g = gt * 128 + wave * 16 + c16;
    #pragma unroll
    for (int ks = 0; ks < 4; ++ks)
      Bfrag[gt][ks] = *(const bf16x8*)(Whh_bf + g * HID + ks * 32 + kg * 8);
  }

  const int aoff = (c16 & 1) * HID + kg * 8;   // A-frag: h[c16&1][kg*8..]
  const float* Pj = P + jfull;
  float cstate = 0.f;

  __syncthreads();

  // prefetch step 0's P row
  int ch = chars[row][0];
  const float* Pr = Pj + (size_t)ch * GATES;
  float p0 = Pr[0], p1 = Pr[128], p2 = Pr[256], p3 = Pr[384];

  #pragma unroll 1
  for (int t = 0; t < SEQ; ++t) {
    const int rb = t & 1;

    // prefetch NEXT step's char + P row (consumed next iteration; full-step slack)
    const int chn = chars[row][(t + 1) & (SEQ - 1)];
    const float* Pn = Pj + (size_t)chn * GATES;
    const float q0 = Pn[0], q1 = Pn[128], q2 = Pn[256], q3 = Pn[384];

    // h(t-1) @ W_hh^T
    const unsigned short* hb = &hbuf[rb][0][0] + aoff;
    f32x4 acc[4] = {};
    #pragma unroll
    for (int ks = 0; ks < 4; ++ks) {
      const bf16x8 A = *(const bf16x8*)(hb + ks * 32);
      #pragma unroll
      for (int gt = 0; gt < 4; ++gt)
        acc[gt] = __builtin_amdgcn_mfma_f32_16x16x32_bf16(A, Bfrag[gt][ks], acc[gt], 0, 0, 0);
    }

    // select this lane's row: D reg r -> batch row r&1 (regs 0/1)
    const float gi = row ? acc[0][1] : acc[0][0];
    const float gf = row ? acc[1][1] : acc[1][0];
    const float gg = row ? acc[2][1] : acc[2][0];
    const float go = row ? acc[3][1] : acc[3][0];

    const float ip = gi + p0;
    const float fp = gf + p1;
    const float gp = gg + p2;
    const float op = go + p3;
    const float iv = 1.f / (1.f + __expf(-ip));
    const float fv = 1.f / (1.f + __expf(-fp));
    const float gv = 1.f - 2.f / (__expf(2.f * gp) + 1.f);   // tanh
    const float ov = 1.f / (1.f + __expf(-op));
    cstate = fv * cstate + iv * gv;
    const float th = 1.f - 2.f / (__expf(2.f * cstate) + 1.f);
    const float hv = ov * th;

    hbuf[rb ^ 1][row][jfull] = f2bf(hv);     // kg>>1 dup writes same value
    if (t == SEQ - 1) h_last[row][jfull] = hv;

    p0 = q0; p1 = q1; p2 = q2; p3 = q3;
    __syncthreads();
  }

  // classifier: one output per thread: out[b0+erow][v]
  const int erow = tid >> 8;
  const int v    = tid & 255;
  float acc = b_cls[v];
  const float4* w  = (const float4*)(W_cls + v * HID);
  const float4* hh = (const float4*)&h_last[erow][0];
  #pragma unroll
  for (int k = 0; k < HID / 4; ++k) {
    const float4 wv = w[k];
    const float4 hv4 = hh[k];
    acc += wv.x * hv4.x + wv.y * hv4.y + wv.z * hv4.z + wv.w * hv4.w;
  }
  out[(b0 + erow) * VOCAB + v] = acc;
}

extern "C" void kernel_launch(void* const* d_in, const int* in_sizes, int n_in,
                              void* d_out, int out_size, void* d_ws, size_t ws_size,
                              hipStream_t stream) {
  const int*   inputs = (const int*)d_in[0];
  const float* emb    = (const float*)d_in[1];
  const float* W_ih   = (const float*)d_in[2];
  const float* W_hh   = (const float*)d_in[3];
  const float* b_ih   = (const float*)d_in[4];
  const float* b_hh   = (const float*)d_in[5];
  const float* W_cls  = (const float*)d_in[6];
  const float* b_cls  = (const float*)d_in[7];
  float* outp = (float*)d_out;

  float* Ptab = (float*)d_ws;
  unsigned short* Whh_bf = (unsigned short*)((char*)d_ws + VOCAB * GATES * sizeof(float));

  prep_kernel<<<VOCAB + 64, 256, 0, stream>>>(emb, W_ih, W_hh, b_ih, b_hh, Ptab, Whh_bf);
  lstm_kernel<<<BATCH / 2, 512, 0, stream>>>(inputs, Ptab, Whh_bf, W_cls, b_cls, outp);
}

// Round 5
// 334.891 us; speedup vs baseline: 1.1846x; 1.1846x over previous
//
#include <hip/hip_runtime.h>
#include <hip/hip_bf16.h>

#define VOCAB 256
#define EMB   32
#define HID   128
#define GATES 512
#define BATCH 512
#define SEQ   512

typedef __attribute__((ext_vector_type(8))) short bf16x8;
typedef __attribute__((ext_vector_type(4))) float f32x4;

static __device__ __forceinline__ unsigned short f2bf(float f) {
  unsigned int u = __float_as_uint(f);
  return (unsigned short)((u + 0x7fffu + ((u >> 16) & 1u)) >> 16);
}

// ws layout: P[VOCAB][GATES] f32 (512 KB) | Whh_bf16[GATES][HID] (128 KB)
__global__ __launch_bounds__(256) void prep_kernel(
    const float* __restrict__ emb, const float* __restrict__ W_ih,
    const float* __restrict__ W_hh, const float* __restrict__ b_ih,
    const float* __restrict__ b_hh, float* __restrict__ P,
    unsigned short* __restrict__ Whh_bf) {
  const int wg  = blockIdx.x;
  const int tid = threadIdx.x;
  if (wg < VOCAB) {
    __shared__ float e[EMB];
    if (tid < EMB) e[tid] = emb[wg * EMB + tid];
    __syncthreads();
    for (int g = tid; g < GATES; g += 256) {
      float acc = b_ih[g] + b_hh[g];
      const float* w = W_ih + g * EMB;
      #pragma unroll
      for (int k = 0; k < EMB; ++k) acc += e[k] * w[k];
      P[wg * GATES + g] = acc;
    }
  } else {
    const int base = (wg - VOCAB) * 1024 + tid * 4;
    const float4 v = *(const float4*)(W_hh + base);
    ushort4 o;
    o.x = f2bf(v.x); o.y = f2bf(v.y); o.z = f2bf(v.z); o.w = f2bf(v.w);
    *(ushort4*)(Whh_bf + base) = o;
  }
}

// 128 WGs x 512 threads (8 waves = 2/SIMD). WG owns batch rows b0..b0+3.
// Per-CU MFMA cost is invariant in R (M=16 covers R<=16 rows), so R=4 gives
// 2 waves/SIMD latency hiding with EXACTLY one gate output per lane:
//   wave w owns j in [16w,16w+16) for all 4 gate types (4 n-tiles x 4 ks).
//   A row m = h[m&3]  =>  D m-row = 4*kg+reg  =>  acc reg r = batch row r.
//   Lane (c16,kg) owns output (row=kg, j=16w+c16)  [bijective, 512 lanes].
// One barrier per step; next-step P/char prefetch; raw v_rcp on gate chain.
__global__ __launch_bounds__(512, 2) void lstm_kernel(
    const int* __restrict__ inputs, const float* __restrict__ P,
    const unsigned short* __restrict__ Whh_bf,
    const float* __restrict__ W_cls, const float* __restrict__ b_cls,
    float* __restrict__ out) {
  const int wg   = blockIdx.x;
  const int tid  = threadIdx.x;
  const int wave = tid >> 6;          // 0..7
  const int lane = tid & 63;
  const int c16  = lane & 15;
  const int kg   = lane >> 4;         // 0..3
  const int b0   = wg * 4;

  const int row   = kg;                        // this lane's batch row (0..3)
  const int jfull = wave * 16 + c16;           // 0..127 hidden index

  __shared__ unsigned char  chars[4][SEQ];     // 2 KB
  __shared__ unsigned short hbuf[2][4][136];   // [buf][row][k] bf16 (+8 pad), 2.125 KB
  __shared__ float          h_last[4][HID];    // 2 KB

  for (int k = tid; k < 4 * SEQ; k += 512) {
    const int r = k >> 9, t = k & (SEQ - 1);
    chars[r][t] = (unsigned char)(inputs[(b0 + r) * SEQ + t] & 0xff);
  }
  for (int k = tid; k < 2 * 4 * 136; k += 512) ((unsigned short*)hbuf)[k] = 0;

  // B-frags resident: Bfrag[gt][ks] lane (c16,kg) = W_hh[gt*128+16w+c16][ks*32+kg*8..+7]
  bf16x8 Bfrag[4][4];
  #pragma unroll
  for (int gt = 0; gt < 4; ++gt) {
    const int g = gt * 128 + wave * 16 + c16;
    #pragma unroll
    for (int ks = 0; ks < 4; ++ks)
      Bfrag[gt][ks] = *(const bf16x8*)(Whh_bf + g * HID + ks * 32 + kg * 8);
  }

  // A-frag: lane (c16,kg) reads h[c16&3][kg*8 .. +7] (+ks*32)
  const int aoff = (c16 & 3) * 136 + kg * 8;
  const float* Pj = P + jfull;
  float cstate = 0.f;

  __syncthreads();

  // prefetch step 0's P row
  {
    const int ch0 = chars[row][0];
    (void)ch0;
  }
  const float* Pr0 = Pj + (size_t)chars[row][0] * GATES;
  float p0 = Pr0[0], p1 = Pr0[128], p2 = Pr0[256], p3 = Pr0[384];

  #pragma unroll 1
  for (int t = 0; t < SEQ; ++t) {
    const int rb = t & 1;

    // prefetch NEXT step's char + P row (full-step slack)
    const int chn = chars[row][(t + 1) & (SEQ - 1)];
    const float* Pn = Pj + (size_t)chn * GATES;
    const float q0 = Pn[0], q1 = Pn[128], q2 = Pn[256], q3 = Pn[384];

    // h(t-1) @ W_hh^T
    const unsigned short* hb = &hbuf[rb][0][0] + aoff;
    f32x4 acc[4] = {};
    #pragma unroll
    for (int ks = 0; ks < 4; ++ks) {
      const bf16x8 A = *(const bf16x8*)(hb + ks * 32);
      #pragma unroll
      for (int gt = 0; gt < 4; ++gt)
        acc[gt] = __builtin_amdgcn_mfma_f32_16x16x32_bf16(A, Bfrag[gt][ks], acc[gt], 0, 0, 0);
    }

    // select this lane's row: acc reg r = batch row r; static 3-cndmask select
    const float gi = (kg & 2) ? ((kg & 1) ? acc[0][3] : acc[0][2])
                              : ((kg & 1) ? acc[0][1] : acc[0][0]);
    const float gf = (kg & 2) ? ((kg & 1) ? acc[1][3] : acc[1][2])
                              : ((kg & 1) ? acc[1][1] : acc[1][0]);
    const float gg = (kg & 2) ? ((kg & 1) ? acc[2][3] : acc[2][2])
                              : ((kg & 1) ? acc[2][1] : acc[2][0]);
    const float go = (kg & 2) ? ((kg & 1) ? acc[3][3] : acc[3][2])
                              : ((kg & 1) ? acc[3][1] : acc[3][0]);

    const float ip = gi + p0;
    const float fp = gf + p1;
    const float gp = gg + p2;
    const float op = go + p3;
    // sigmoid/tanh with raw v_rcp (1-ulp, fine vs 5.6e-3 threshold)
    const float iv = __builtin_amdgcn_rcpf(1.f + __expf(-ip));
    const float fv = __builtin_amdgcn_rcpf(1.f + __expf(-fp));
    const float gv = 1.f - 2.f * __builtin_amdgcn_rcpf(__expf(2.f * gp) + 1.f);
    const float ov = __builtin_amdgcn_rcpf(1.f + __expf(-op));
    cstate = fv * cstate + iv * gv;
    const float th = 1.f - 2.f * __builtin_amdgcn_rcpf(__expf(2.f * cstate) + 1.f);
    const float hv = ov * th;

    hbuf[rb ^ 1][row][jfull] = f2bf(hv);
    if (t == SEQ - 1) h_last[row][jfull] = hv;

    p0 = q0; p1 = q1; p2 = q2; p3 = q3;
    __syncthreads();
  }

  // classifier: 4 rows x 256 vocab = 1024 outputs, 2 per thread
  const int erow = tid >> 7;          // 0..3
  const int ej   = tid & 127;
  #pragma unroll
  for (int half = 0; half < 2; ++half) {
    const int v = ej + half * 128;
    float acc = b_cls[v];
    const float4* w  = (const float4*)(W_cls + v * HID);
    const float4* hh = (const float4*)&h_last[erow][0];
    #pragma unroll
    for (int k = 0; k < HID / 4; ++k) {
      const float4 wv = w[k];
      const float4 hv4 = hh[k];
      acc += wv.x * hv4.x + wv.y * hv4.y + wv.z * hv4.z + wv.w * hv4.w;
    }
    out[(b0 + erow) * VOCAB + v] = acc;
  }
}

extern "C" void kernel_launch(void* const* d_in, const int* in_sizes, int n_in,
                              void* d_out, int out_size, void* d_ws, size_t ws_size,
                              hipStream_t stream) {
  const int*   inputs = (const int*)d_in[0];
  const float* emb    = (const float*)d_in[1];
  const float* W_ih   = (const float*)d_in[2];
  const float* W_hh   = (const float*)d_in[3];
  const float* b_ih   = (const float*)d_in[4];
  const float* b_hh   = (const float*)d_in[5];
  const float* W_cls  = (const float*)d_in[6];
  const float* b_cls  = (const float*)d_in[7];
  float* outp = (float*)d_out;

  float* Ptab = (float*)d_ws;
  unsigned short* Whh_bf = (unsigned short*)((char*)d_ws + VOCAB * GATES * sizeof(float));

  prep_kernel<<<VOCAB + 64, 256, 0, stream>>>(emb, W_ih, W_hh, b_ih, b_hh, Ptab, Whh_bf);
  lstm_kernel<<<BATCH / 4, 512, 0, stream>>>(inputs, Ptab, Whh_bf, W_cls, b_cls, outp);
}